// Round 10
// baseline (273.985 us; speedup 1.0000x reference)
//
#include <hip/hip_runtime.h>

// N=1024, F_NODE=64, F_EDGE=32, F_IN=160.
// out[a,j] = sum_b gated(a,b,j);  gated = relu(Hp)*sigmoid(Ha)
// Hp[a,b,j] = A[a,b]*(H[a]·W[0:64,j] + H[b]·W[64:128,j] + E[a,b]·W[128:160,j]) + bias[j]
// A in {0,1}: A=0 pairs contribute g0[j]=relu(bias)*sigmoid(bias) (constant).
//
// R18 (this round): hoist the linear terms (5x FLOP cut).
//  - H[b]·W[64:128,j] is independent of a; R17 recomputed it in every
//    block (16 of 24 MFMAs/tile). prep2 now precomputes
//      U1 = H·W[0:64]+bias, U2 = H·W[64:128] (and V1/V2 for W_att),
//    U2/V2 stored TRANSPOSED [j][b] so mga reads aligned float4 C-frags.
//  - mga COMPMT: 2 MFMAs (E seg, K=32) + U2t/V2t float4 L2 loads folded
//    into the MFMA C operand. H loads gone. Same bf16 math as before,
//    computed once instead of 1024x.
//  - E staging unchanged from R17: global_load_lds quad-buffer, counted
//    vmcnt(4/2/0) + raw s_barrier, permuted conflict-free layout.
//  - U2t/V2t = 512KB total, L2-resident, reused by all blocks.
#define NN 1024
#define FN 64
#define FE 32
#define FIN 160

#pragma clang diagnostic ignored "-Waddress-space-conversion"

typedef __bf16 bf16x8 __attribute__((ext_vector_type(8)));
typedef short  short8 __attribute__((ext_vector_type(8)));
typedef float  f32x4  __attribute__((ext_vector_type(4)));
typedef __attribute__((address_space(1))) const unsigned int gu32;
typedef __attribute__((address_space(3))) unsigned int lu32;

static __device__ __forceinline__ unsigned short f2b(float x){
    unsigned int u = __float_as_uint(x);
    unsigned int r = (u + 0x7fffu + ((u >> 16) & 1u)) >> 16;
    return (unsigned short)r;
}

static __device__ __forceinline__ float fast_sigmoid(float y){
    return __builtin_amdgcn_rcpf(1.0f + __expf(-y));
}

static __device__ __forceinline__ bf16x8 ldfrag(const unsigned short* p){
    return __builtin_bit_cast(bf16x8, *(const short8*)(p));
}

// pack two f32 -> (bf16 lo, bf16 hi) by truncation: one v_perm_b32
static __device__ __forceinline__ unsigned packtrunc(float lo, float hi){
    return __builtin_amdgcn_perm(__float_as_uint(hi), __float_as_uint(lo), 0x07060302u);
}

#define MF(A,B,C) __builtin_amdgcn_mfma_f32_16x16x32_bf16((A),(B),(C),0,0,0)

// blocks 0..63: H f32 -> Hb bf16 (1024x64); block 64/65: W/Wa -> Wt[j][k] bf16
__global__ void prep(const float* __restrict__ H, const float* __restrict__ W,
                     const float* __restrict__ Wa,
                     unsigned short* __restrict__ Hb,
                     unsigned short* __restrict__ WtE,
                     unsigned short* __restrict__ WtA){
    int bid = blockIdx.x, tid = threadIdx.x;
    if (bid < 64){
        int i = (bid*256 + tid)*4;
        float4 v = *(const float4*)(H + i);
        ushort4 o;
        o.x = f2b(v.x); o.y = f2b(v.y); o.z = f2b(v.z); o.w = f2b(v.w);
        *(ushort4*)(Hb + i) = o;
    } else {
        const float* src = (bid == 64) ? W : Wa;
        unsigned short* dst = (bid == 64) ? WtE : WtA;
        for (int idx = tid; idx < FIN*FN; idx += 256){
            int k = idx >> 6, j = idx & 63;
            dst[j*FIN + k] = f2b(src[idx]);
        }
    }
}

// 16 blocks x 4 waves; wave handles 16 H-rows x all 64 j.
// U1[r][j] = bias[j] + H[r]·W[0:64,j]   (row-major, per-row-a reads)
// U2t[j][r] = H[r]·W[64:128,j]          (transposed: float4 C-frag reads)
// V1/V2t likewise for W_att.
// MFMA A: m=lane&15 (row), k=quad*8+i; B: k, n=lane&15; D: col=lane&15,
// row=quad*4+reg [m89/m91].
__global__ void prep2(const unsigned short* __restrict__ Hb,
                      const unsigned short* __restrict__ WtE,
                      const unsigned short* __restrict__ WtA,
                      const float* __restrict__ bias,
                      float* __restrict__ U1, float* __restrict__ V1,
                      float* __restrict__ U2t, float* __restrict__ V2t){
    int tid = threadIdx.x, wave = tid >> 6, lane = tid & 63;
    int col = lane & 15, quad = lane >> 4;
    int r0  = blockIdx.x*64 + wave*16;
    bf16x8 h0 = ldfrag(Hb + (r0 + col)*FN + quad*8);        // k 0:32
    bf16x8 h1 = ldfrag(Hb + (r0 + col)*FN + 32 + quad*8);   // k 32:64
    #pragma unroll
    for (int jt = 0; jt < 4; jt++){
        int n = jt*16 + col;
        float bj = bias[n];
        f32x4 cb = {bj, bj, bj, bj};
        f32x4 z  = {0.f, 0.f, 0.f, 0.f};
        bf16x8 b0 = ldfrag(WtE + n*FIN + quad*8);
        bf16x8 b1 = ldfrag(WtE + n*FIN + 32 + quad*8);
        f32x4 u1 = MF(h1, b1, MF(h0, b0, cb));
        b0 = ldfrag(WtE + n*FIN + 64 + quad*8);
        b1 = ldfrag(WtE + n*FIN + 96 + quad*8);
        f32x4 u2 = MF(h1, b1, MF(h0, b0, z));
        b0 = ldfrag(WtA + n*FIN + quad*8);
        b1 = ldfrag(WtA + n*FIN + 32 + quad*8);
        f32x4 v1 = MF(h1, b1, MF(h0, b0, cb));
        b0 = ldfrag(WtA + n*FIN + 64 + quad*8);
        b1 = ldfrag(WtA + n*FIN + 96 + quad*8);
        f32x4 v2 = MF(h1, b1, MF(h0, b0, z));
        #pragma unroll
        for (int r = 0; r < 4; r++){
            U1[(r0 + quad*4 + r)*FN + n] = u1[r];
            V1[(r0 + quad*4 + r)*FN + n] = v1[r];
        }
        *(f32x4*)(U2t + (size_t)n*NN + r0 + quad*4) = u2;
        *(f32x4*)(V2t + (size_t)n*NN + r0 + quad*4) = v2;
    }
}

// Stage tile su (64 E-rows, 8KB f32) into Et[buf_]. Physical LDS chunk
// L = is*256 + tid holds logical chunk decoded as:
//   c=L&15, q=(L>>4)&3, s=(L>>6)&1, mt=(L>>7)&1, mh=(L>>8)&1;
//   row = mh*32+mt*16+c; float offset = row*32+(q*2+s)*4.
// => COMPMT's ds_read_b128 reads 64 consecutive chunks at base+lane*16:
//    conflict-free. Per wave: 2 gload_lds vmem ops (the vmcnt currency).
#define STAGE(buf_, su_) do {                                               \
    const float* gt_ = E + (size_t)a*(NN*FE) + (su_)*2048;                  \
    _Pragma("unroll")                                                       \
    for (int is_ = 0; is_ < 2; is_++){                                      \
        int L_   = is_*256 + tid;                                           \
        int row_ = ((L_>>8)&1)*32 + ((L_>>7)&1)*16 + (L_ & 15);             \
        int src_ = row_*32 + ((((L_>>4)&3)*2 + ((L_>>6)&1))*4);             \
        __builtin_amdgcn_global_load_lds(                                   \
            (gu32*)(gt_ + src_),                                            \
            (lu32*)(&Et[buf_][is_*1024 + wave*256]), 16, 0, 0);             \
    }                                                                       \
} while(0)

// One m-tile: 2 conflict-free ds_read_b128 (E), pack, per tl: U2t/V2t
// float4 (L2-hot) folded into MFMA C, 1 MFMA per matrix, gate+mask.
#define COMPMT(buf_, su_, mt_) do {                                         \
    const float* tp_ = &Et[buf_][(mh*2 + (mt_))*512 + quad*64 + col*4];     \
    float4 v0_ = *(const float4*)(tp_);                                     \
    float4 v1_ = *(const float4*)(tp_ + 256);                               \
    int g0_ = (su_)*64 + mh*32 + (mt_)*16 + quad*4;                         \
    int4 pk_;                                                               \
    pk_.x = (int)packtrunc(v0_.x, v0_.y);                                   \
    pk_.y = (int)packtrunc(v0_.z, v0_.w);                                   \
    pk_.z = (int)packtrunc(v1_.x, v1_.y);                                   \
    pk_.w = (int)packtrunc(v1_.z, v1_.w);                                   \
    bf16x8 ef_ = __builtin_bit_cast(bf16x8, pk_);                           \
    _Pragma("unroll")                                                       \
    for (int tl = 0; tl < 2; tl++){                                         \
        int n_ = (2*half + tl)*16 + col;                                    \
        f32x4 u2_ = *(const f32x4*)(U2t + (size_t)n_*NN + g0_);             \
        f32x4 w2_ = *(const f32x4*)(V2t + (size_t)n_*NN + g0_);             \
        f32x4 cw_, ca_;                                                     \
        _Pragma("unroll")                                                   \
        for (int r4 = 0; r4 < 4; r4++){                                     \
            cw_[r4] = u1s[tl] + u2_[r4];                                    \
            ca_[r4] = v1s[tl] + w2_[r4];                                    \
        }                                                                   \
        f32x4 pw_ = MF(ef_, Bw[tl], cw_);                                   \
        f32x4 pa_ = MF(ef_, Ba[tl], ca_);                                   \
        _Pragma("unroll")                                                   \
        for (int r4 = 0; r4 < 4; r4++){                                     \
            float am_ = amask[g0_ + r4];                                    \
            float f_  = fmaxf(pw_[r4], 0.f) * fast_sigmoid(pa_[r4]);        \
            acc[tl] += am_ * f_;                                            \
        }                                                                   \
    }                                                                       \
} while(0)

// One block per row a. Stream all 1024 b-rows of E[a] through quad-
// buffered LDS tiles with counted-vmcnt pipelining; linear terms come
// precomputed from U1/U2t/V1/V2t.
// 4 waves, wave=(half<<1)|mh: half -> j-tiles {2half,2half+1}, mh -> 32-row
// half of each 64-row tile.
__global__ __launch_bounds__(256, 4) void mga_fused(
    const float* __restrict__ A,
    const float* __restrict__ E,
    const unsigned short* __restrict__ WtE, const unsigned short* __restrict__ WtA,
    const float* __restrict__ U1, const float* __restrict__ V1,
    const float* __restrict__ U2t, const float* __restrict__ V2t,
    const float* __restrict__ bias, float* __restrict__ out)
{
    int a    = blockIdx.x;
    int tid  = threadIdx.x;
    int wave = tid >> 6, lane = tid & 63;
    int col  = lane & 15, quad = lane >> 4;
    int half = wave >> 1, mh = wave & 1;

    __shared__ float Et[4][2048];          // 4 x 8KB staged E tiles (32KB)
    __shared__ float amask[NN];            // A row as f32 (values are 0.0/1.0)
    __shared__ int wsum[4];
    float* red = (float*)Et;               // aliased: red used only after loop

    // ---- issue A-row load first
    int b0 = wave*256 + lane*4;
    float4 av = *(const float4*)(A + (size_t)a*NN + b0);

    // Held state: E-segment B-frags + per-a linear terms (tiny)
    int n0 = (2*half)*16 + col, n1 = n0 + 16;
    bf16x8 Bw[2], Ba[2];
    Bw[0] = ldfrag(WtE + n0*FIN + 128 + quad*8);
    Bw[1] = ldfrag(WtE + n1*FIN + 128 + quad*8);
    Ba[0] = ldfrag(WtA + n0*FIN + 128 + quad*8);
    Ba[1] = ldfrag(WtA + n1*FIN + 128 + quad*8);
    float u1s[2] = {U1[a*FN + n0], U1[a*FN + n1]};
    float v1s[2] = {V1[a*FN + n0], V1[a*FN + n1]};
    float acc[2] = {0.f, 0.f};

    // ---- publish A row to LDS + count nonzeros
    *(float4*)(amask + b0) = av;
    int m = 0;
    m += (av.x != 0.f) ? 1 : 0;
    m += (av.y != 0.f) ? 1 : 0;
    m += (av.z != 0.f) ? 1 : 0;
    m += (av.w != 0.f) ? 1 : 0;
    #pragma unroll
    for (int d = 1; d < 64; d <<= 1) m += __shfl_xor(m, d, 64);
    if (lane == 0) wsum[wave] = m;

    // ---- prologue: stage tiles 0,1; ONE full drain
    STAGE(0, 0);
    STAGE(1, 1);
    __syncthreads();
    int c1 = wsum[0] + wsum[1] + wsum[2] + wsum[3];

    // ---- counted-vmcnt pipeline: one raw barrier per tile, stage ops in
    // flight across it. Steady-state outstanding at wait = 4 (2 stages).
    #pragma unroll
    for (int su = 0; su < 16; su++){
        int buf = su & 3;
        if (su + 2 < 16) STAGE((su + 2) & 3, su + 2);
        if (su < 14)      { asm volatile("s_waitcnt vmcnt(4)" ::: "memory"); }
        else if (su == 14){ asm volatile("s_waitcnt vmcnt(2)" ::: "memory"); }
        else              { asm volatile("s_waitcnt vmcnt(0)" ::: "memory"); }
        __builtin_amdgcn_s_barrier();      // tile su resident block-wide
        COMPMT(buf, su, 0);
        COMPMT(buf, su, 1);
    }

    // red aliases Et: all waves are past the iter-13 barrier here, so the
    // last Et[0..1] readers finished long before these writes.
    #pragma unroll
    for (int tl = 0; tl < 2; tl++)
        red[(wave*4 + quad)*FN + (2*half + tl)*16 + col] = acc[tl];
    __syncthreads();
    if (tid < FN){
        int rbase = (tid >= 32) ? 8 : 0;   // waves 0,1: j<32; waves 2,3: j>=32
        float sum = 0.f;
        #pragma unroll
        for (int r = 0; r < 8; r++) sum += red[(rbase + r)*FN + tid];
        float bj = bias[tid];
        float g0 = fmaxf(bj, 0.f) * fast_sigmoid(bj);
        out[(size_t)a*FN + tid] = sum + (float)(NN - c1) * g0;
    }
}

extern "C" void kernel_launch(void* const* d_in, const int* in_sizes, int n_in,
                              void* d_out, int out_size, void* d_ws, size_t ws_size,
                              hipStream_t stream) {
    const float* H    = (const float*)d_in[0];
    const float* A    = (const float*)d_in[1];
    const float* E    = (const float*)d_in[2];
    const float* W    = (const float*)d_in[3];
    const float* Wa   = (const float*)d_in[4];
    const float* bias = (const float*)d_in[5];
    float* out = (float*)d_out;

    unsigned short* Hb   = (unsigned short*)d_ws;         // 1024*64 bf16
    unsigned short* WtE  = Hb + NN*FN;                    // 64*160
    unsigned short* WtA  = WtE + FN*FIN;                  // 64*160
    float* U1  = (float*)(WtA + FN*FIN);                  // 1024*64 f32
    float* V1  = U1 + NN*FN;
    float* U2t = V1 + NN*FN;                              // [64][1024] f32
    float* V2t = U2t + (size_t)FN*NN;

    prep     <<<dim3(66), dim3(256), 0, stream>>>(H, W, Wa, Hb, WtE, WtA);
    prep2    <<<dim3(16), dim3(256), 0, stream>>>(Hb, WtE, WtA, bias, U1, V1, U2t, V2t);
    mga_fused<<<dim3(NN), dim3(256), 0, stream>>>(A, E, WtE, WtA, U1, V1, U2t, V2t, bias, out);
}

// Round 11
// 263.822 us; speedup vs baseline: 1.0385x; 1.0385x over previous
//
#include <hip/hip_runtime.h>

// N=1024, F_NODE=64, F_EDGE=32, F_IN=160.
// out[a,j] = sum_b gated(a,b,j);  gated = relu(Hp)*sigmoid(Ha)
// Hp[a,b,j] = A[a,b]*(H[a]·W[0:64,j] + H[b]·W[64:128,j] + E[a,b]·W[128:160,j]) + bias[j]
// A in {0,1}: A=0 pairs contribute g0[j]=relu(bias)*sigmoid(bias) (constant).
//
// R19 (this round): VMEM-free compute phase (T14 issue-early U2/V2).
//  - R18's U2t/V2t loads sat INSIDE the compute phase: compiler-inserted
//    waitcnt before their use counted the in-flight stage DMAs -> drained
//    the pipeline every iteration + raw L2 latency (108us, MFMA 3%).
//    Same mechanism explains R17's H-loads nullifying counted-vmcnt.
//  - Now: tile su+1's 8 x f32x4 U2t/V2t frags prefetched into double-
//    buffered registers ALONGSIDE STAGE(su+2), before the wait. Unified
//    vmcnt currency: 2 stage + 8 pf per iter -> steady wait vmcnt(10)
//    (tile su resident + pf(su) landed; su+1/su+2 stay in flight).
//    Tail: vmcnt(8) @ su=14, vmcnt(0) @ su=15. Loop body has ZERO vmem
//    loads: only ds_read/VALU/MFMA -> nothing forces a drain.
//  - +64 VGPR for pf buffers -> __launch_bounds__(256,3) (cap 168,
//    live ~116, no spill; R18 ran ~3 blocks/CU anyway).
//  - Unchanged: prep/prep2 linear-term hoist (5x FLOP cut), E quad-buffer
//    gload_lds staging with permuted conflict-free layout, A-mask LDS,
//    (N-c1)*g0 constant path, full unroll (all indices literal).
#define NN 1024
#define FN 64
#define FE 32
#define FIN 160

#pragma clang diagnostic ignored "-Waddress-space-conversion"

typedef __bf16 bf16x8 __attribute__((ext_vector_type(8)));
typedef short  short8 __attribute__((ext_vector_type(8)));
typedef float  f32x4  __attribute__((ext_vector_type(4)));
typedef __attribute__((address_space(1))) const unsigned int gu32;
typedef __attribute__((address_space(3))) unsigned int lu32;

static __device__ __forceinline__ unsigned short f2b(float x){
    unsigned int u = __float_as_uint(x);
    unsigned int r = (u + 0x7fffu + ((u >> 16) & 1u)) >> 16;
    return (unsigned short)r;
}

static __device__ __forceinline__ float fast_sigmoid(float y){
    return __builtin_amdgcn_rcpf(1.0f + __expf(-y));
}

static __device__ __forceinline__ bf16x8 ldfrag(const unsigned short* p){
    return __builtin_bit_cast(bf16x8, *(const short8*)(p));
}

// pack two f32 -> (bf16 lo, bf16 hi) by truncation: one v_perm_b32
static __device__ __forceinline__ unsigned packtrunc(float lo, float hi){
    return __builtin_amdgcn_perm(__float_as_uint(hi), __float_as_uint(lo), 0x07060302u);
}

#define MF(A,B,C) __builtin_amdgcn_mfma_f32_16x16x32_bf16((A),(B),(C),0,0,0)

// blocks 0..63: H f32 -> Hb bf16 (1024x64); block 64/65: W/Wa -> Wt[j][k] bf16
__global__ void prep(const float* __restrict__ H, const float* __restrict__ W,
                     const float* __restrict__ Wa,
                     unsigned short* __restrict__ Hb,
                     unsigned short* __restrict__ WtE,
                     unsigned short* __restrict__ WtA){
    int bid = blockIdx.x, tid = threadIdx.x;
    if (bid < 64){
        int i = (bid*256 + tid)*4;
        float4 v = *(const float4*)(H + i);
        ushort4 o;
        o.x = f2b(v.x); o.y = f2b(v.y); o.z = f2b(v.z); o.w = f2b(v.w);
        *(ushort4*)(Hb + i) = o;
    } else {
        const float* src = (bid == 64) ? W : Wa;
        unsigned short* dst = (bid == 64) ? WtE : WtA;
        for (int idx = tid; idx < FIN*FN; idx += 256){
            int k = idx >> 6, j = idx & 63;
            dst[j*FIN + k] = f2b(src[idx]);
        }
    }
}

// 16 blocks x 4 waves; wave handles 16 H-rows x all 64 j.
// U1[r][j] = bias[j] + H[r]·W[0:64,j]   (row-major, per-row-a reads)
// U2t[j][r] = H[r]·W[64:128,j]          (transposed: float4 C-frag reads)
// V1/V2t likewise for W_att.
__global__ void prep2(const unsigned short* __restrict__ Hb,
                      const unsigned short* __restrict__ WtE,
                      const unsigned short* __restrict__ WtA,
                      const float* __restrict__ bias,
                      float* __restrict__ U1, float* __restrict__ V1,
                      float* __restrict__ U2t, float* __restrict__ V2t){
    int tid = threadIdx.x, wave = tid >> 6, lane = tid & 63;
    int col = lane & 15, quad = lane >> 4;
    int r0  = blockIdx.x*64 + wave*16;
    bf16x8 h0 = ldfrag(Hb + (r0 + col)*FN + quad*8);        // k 0:32
    bf16x8 h1 = ldfrag(Hb + (r0 + col)*FN + 32 + quad*8);   // k 32:64
    #pragma unroll
    for (int jt = 0; jt < 4; jt++){
        int n = jt*16 + col;
        float bj = bias[n];
        f32x4 cb = {bj, bj, bj, bj};
        f32x4 z  = {0.f, 0.f, 0.f, 0.f};
        bf16x8 b0 = ldfrag(WtE + n*FIN + quad*8);
        bf16x8 b1 = ldfrag(WtE + n*FIN + 32 + quad*8);
        f32x4 u1 = MF(h1, b1, MF(h0, b0, cb));
        b0 = ldfrag(WtE + n*FIN + 64 + quad*8);
        b1 = ldfrag(WtE + n*FIN + 96 + quad*8);
        f32x4 u2 = MF(h1, b1, MF(h0, b0, z));
        b0 = ldfrag(WtA + n*FIN + quad*8);
        b1 = ldfrag(WtA + n*FIN + 32 + quad*8);
        f32x4 v1 = MF(h1, b1, MF(h0, b0, cb));
        b0 = ldfrag(WtA + n*FIN + 64 + quad*8);
        b1 = ldfrag(WtA + n*FIN + 96 + quad*8);
        f32x4 v2 = MF(h1, b1, MF(h0, b0, z));
        #pragma unroll
        for (int r = 0; r < 4; r++){
            U1[(r0 + quad*4 + r)*FN + n] = u1[r];
            V1[(r0 + quad*4 + r)*FN + n] = v1[r];
        }
        *(f32x4*)(U2t + (size_t)n*NN + r0 + quad*4) = u2;
        *(f32x4*)(V2t + (size_t)n*NN + r0 + quad*4) = v2;
    }
}

// Stage tile su (64 E-rows, 8KB f32) into Et[buf_]. Permuted so COMPMT's
// ds_read_b128 reads 64 consecutive 16B chunks at base+lane*16 (free).
// Per wave: 2 gload_lds vmem ops.
#define STAGE(buf_, su_) do {                                               \
    const float* gt_ = E + (size_t)a*(NN*FE) + (su_)*2048;                  \
    _Pragma("unroll")                                                       \
    for (int is_ = 0; is_ < 2; is_++){                                      \
        int L_   = is_*256 + tid;                                           \
        int row_ = ((L_>>8)&1)*32 + ((L_>>7)&1)*16 + (L_ & 15);             \
        int src_ = row_*32 + ((((L_>>4)&3)*2 + ((L_>>6)&1))*4);             \
        __builtin_amdgcn_global_load_lds(                                   \
            (gu32*)(gt_ + src_),                                            \
            (lu32*)(&Et[buf_][is_*1024 + wave*256]), 16, 0, 0);             \
    }                                                                       \
} while(0)

// Prefetch tile su_'s 8 x f32x4 U2t/V2t fragments into pf buffer pf_.
// Issued BEFORE the waitcnt -> consumed one iteration later (T14).
// Per wave: 8 vmem ops (L2-hot, 512KB shared working set).
#define PFU2(pf_, su_) do {                                                 \
    _Pragma("unroll")                                                       \
    for (int mt_ = 0; mt_ < 2; mt_++){                                      \
        int g0_ = (su_)*64 + mh*32 + mt_*16 + quad*4;                       \
        _Pragma("unroll")                                                   \
        for (int tl_ = 0; tl_ < 2; tl_++){                                  \
            int n_ = (2*half + tl_)*16 + col;                               \
            pu2[pf_][mt_][tl_] = *(const f32x4*)(U2t + (size_t)n_*NN + g0_);\
            pv2[pf_][mt_][tl_] = *(const f32x4*)(V2t + (size_t)n_*NN + g0_);\
        }                                                                   \
    }                                                                       \
} while(0)

// One m-tile: 2 conflict-free ds_read_b128 (E), pack, per tl: prefetched
// U2/V2 regs folded into MFMA C, 1 MFMA per matrix, gate+mask.
// NO VMEM loads here -> compiler has nothing to drain vmcnt on.
#define COMPMT(buf_, pf_, su_, mt_) do {                                    \
    const float* tp_ = &Et[buf_][(mh*2 + (mt_))*512 + quad*64 + col*4];     \
    float4 v0_ = *(const float4*)(tp_);                                     \
    float4 v1_ = *(const float4*)(tp_ + 256);                               \
    int g0_ = (su_)*64 + mh*32 + (mt_)*16 + quad*4;                         \
    int4 pk_;                                                               \
    pk_.x = (int)packtrunc(v0_.x, v0_.y);                                   \
    pk_.y = (int)packtrunc(v0_.z, v0_.w);                                   \
    pk_.z = (int)packtrunc(v1_.x, v1_.y);                                   \
    pk_.w = (int)packtrunc(v1_.z, v1_.w);                                   \
    bf16x8 ef_ = __builtin_bit_cast(bf16x8, pk_);                           \
    _Pragma("unroll")                                                       \
    for (int tl = 0; tl < 2; tl++){                                         \
        f32x4 cw_, ca_;                                                     \
        _Pragma("unroll")                                                   \
        for (int r4 = 0; r4 < 4; r4++){                                     \
            cw_[r4] = u1s[tl] + pu2[pf_][(mt_)][tl][r4];                    \
            ca_[r4] = v1s[tl] + pv2[pf_][(mt_)][tl][r4];                    \
        }                                                                   \
        f32x4 pw_ = MF(ef_, Bw[tl], cw_);                                   \
        f32x4 pa_ = MF(ef_, Ba[tl], ca_);                                   \
        _Pragma("unroll")                                                   \
        for (int r4 = 0; r4 < 4; r4++){                                     \
            float am_ = amask[g0_ + r4];                                    \
            float f_  = fmaxf(pw_[r4], 0.f) * fast_sigmoid(pa_[r4]);        \
            acc[tl] += am_ * f_;                                            \
        }                                                                   \
    }                                                                       \
} while(0)

// One block per row a. E streamed through quad-buffered LDS (counted
// vmcnt), U2/V2 through double-buffered registers (issue-early), linear
// terms precomputed. 4 waves, wave=(half<<1)|mh.
__global__ __launch_bounds__(256, 3) void mga_fused(
    const float* __restrict__ A,
    const float* __restrict__ E,
    const unsigned short* __restrict__ WtE, const unsigned short* __restrict__ WtA,
    const float* __restrict__ U1, const float* __restrict__ V1,
    const float* __restrict__ U2t, const float* __restrict__ V2t,
    const float* __restrict__ bias, float* __restrict__ out)
{
    int a    = blockIdx.x;
    int tid  = threadIdx.x;
    int wave = tid >> 6, lane = tid & 63;
    int col  = lane & 15, quad = lane >> 4;
    int half = wave >> 1, mh = wave & 1;

    __shared__ float Et[4][2048];          // 4 x 8KB staged E tiles (32KB)
    __shared__ float amask[NN];            // A row as f32 (values are 0.0/1.0)
    __shared__ int wsum[4];
    float* red = (float*)Et;               // aliased: used only after loop

    // ---- issue A-row load first
    int b0 = wave*256 + lane*4;
    float4 av = *(const float4*)(A + (size_t)a*NN + b0);

    // Held state: E-segment B-frags + per-a linear terms
    int n0 = (2*half)*16 + col, n1 = n0 + 16;
    bf16x8 Bw[2], Ba[2];
    Bw[0] = ldfrag(WtE + n0*FIN + 128 + quad*8);
    Bw[1] = ldfrag(WtE + n1*FIN + 128 + quad*8);
    Ba[0] = ldfrag(WtA + n0*FIN + 128 + quad*8);
    Ba[1] = ldfrag(WtA + n1*FIN + 128 + quad*8);
    float u1s[2] = {U1[a*FN + n0], U1[a*FN + n1]};
    float v1s[2] = {V1[a*FN + n0], V1[a*FN + n1]};
    float acc[2] = {0.f, 0.f};

    // Double-buffered U2/V2 prefetch registers (all indices literal)
    f32x4 pu2[2][2][2], pv2[2][2][2];

    // ---- publish A row to LDS + count nonzeros
    *(float4*)(amask + b0) = av;
    int m = 0;
    m += (av.x != 0.f) ? 1 : 0;
    m += (av.y != 0.f) ? 1 : 0;
    m += (av.z != 0.f) ? 1 : 0;
    m += (av.w != 0.f) ? 1 : 0;
    #pragma unroll
    for (int d = 1; d < 64; d <<= 1) m += __shfl_xor(m, d, 64);
    if (lane == 0) wsum[wave] = m;

    // ---- prologue: stage tiles 0,1 + prefetch pf(0); ONE full drain
    STAGE(0, 0);
    STAGE(1, 1);
    PFU2(0, 0);
    __syncthreads();
    int c1 = wsum[0] + wsum[1] + wsum[2] + wsum[3];

    // ---- counted-vmcnt pipeline. Issue order per iter su:
    //   STAGE(su+2) [2], PFU2(su+1) [8], wait, barrier, compute(su).
    // Steady: ops newer than pf(su) = 2+8 = 10 -> vmcnt(10).
    #pragma unroll
    for (int su = 0; su < 16; su++){
        int buf = su & 3;
        if (su + 2 < 16) STAGE((su + 2) & 3, su + 2);
        if (su + 1 < 16) PFU2((su + 1) & 1, su + 1);
        if (su < 14)      { asm volatile("s_waitcnt vmcnt(10)" ::: "memory"); }
        else if (su == 14){ asm volatile("s_waitcnt vmcnt(8)"  ::: "memory"); }
        else              { asm volatile("s_waitcnt vmcnt(0)"  ::: "memory"); }
        __builtin_amdgcn_s_barrier();      // tile su resident block-wide
        COMPMT(buf, su & 1, su, 0);
        COMPMT(buf, su & 1, su, 1);
    }

    // red aliases Et: all waves are past the iter-13 barrier here.
    #pragma unroll
    for (int tl = 0; tl < 2; tl++)
        red[(wave*4 + quad)*FN + (2*half + tl)*16 + col] = acc[tl];
    __syncthreads();
    if (tid < FN){
        int rbase = (tid >= 32) ? 8 : 0;   // waves 0,1: j<32; waves 2,3: j>=32
        float sum = 0.f;
        #pragma unroll
        for (int r = 0; r < 8; r++) sum += red[(rbase + r)*FN + tid];
        float bj = bias[tid];
        float g0 = fmaxf(bj, 0.f) * fast_sigmoid(bj);
        out[(size_t)a*FN + tid] = sum + (float)(NN - c1) * g0;
    }
}

extern "C" void kernel_launch(void* const* d_in, const int* in_sizes, int n_in,
                              void* d_out, int out_size, void* d_ws, size_t ws_size,
                              hipStream_t stream) {
    const float* H    = (const float*)d_in[0];
    const float* A    = (const float*)d_in[1];
    const float* E    = (const float*)d_in[2];
    const float* W    = (const float*)d_in[3];
    const float* Wa   = (const float*)d_in[4];
    const float* bias = (const float*)d_in[5];
    float* out = (float*)d_out;

    unsigned short* Hb   = (unsigned short*)d_ws;         // 1024*64 bf16
    unsigned short* WtE  = Hb + NN*FN;                    // 64*160
    unsigned short* WtA  = WtE + FN*FIN;                  // 64*160
    float* U1  = (float*)(WtA + FN*FIN);                  // 1024*64 f32
    float* V1  = U1 + NN*FN;
    float* U2t = V1 + NN*FN;                              // [64][1024] f32
    float* V2t = U2t + (size_t)FN*NN;

    prep     <<<dim3(66), dim3(256), 0, stream>>>(H, W, Wa, Hb, WtE, WtA);
    prep2    <<<dim3(16), dim3(256), 0, stream>>>(Hb, WtE, WtA, bias, U1, V1, U2t, V2t);
    mga_fused<<<dim3(NN), dim3(256), 0, stream>>>(A, E, WtE, WtA, U1, V1, U2t, V2t, bias, out);
}